// Round 2
// baseline (689.394 us; speedup 1.0000x reference)
//
#include <hip/hip_runtime.h>

#define NPTS   100000
#define HW     50          // hidden width == Q
#define NHID   4
#define DTc    0.6f
#define LBc   (-1.0f)
#define UBc    1.0f
#define PPB    64          // points per 256-thread block (4 lanes/point)
#define NBLK   ((2*NPTS + PPB - 1) / PPB)   // 3125 exactly

// quad_perm broadcast within each 4-lane group (pure VALU, no LDS pipe)
template <int CTRL>
__device__ __forceinline__ float qperm(float v) {
    return __int_as_float(__builtin_amdgcn_mov_dpp(__float_as_int(v), CTRL, 0xF, 0xF, true));
}

// tanh(z) = 1 - 2/(exp(2z)+1): 2 trans ops, ~3 ulp, saturates correctly at +-inf
__device__ __forceinline__ float fast_tanh(float z) {
    float e = __expf(2.0f * z);
    return 1.0f - 2.0f * __builtin_amdgcn_rcpf(e + 1.0f);
}

__global__ __launch_bounds__(256) void pinn_kdv_kernel(
    const float* __restrict__ x1, const float* __restrict__ x2,
    const float* __restrict__ W_in, const float* __restrict__ b_in,
    const float* __restrict__ W_hid, const float* __restrict__ b_hid,
    const float* __restrict__ W_out, const float* __restrict__ b_out,
    const float* __restrict__ lambda_1, const float* __restrict__ lambda_2,
    const float* __restrict__ irk_alpha, const float* __restrict__ irk_beta,
    float* __restrict__ out)
{
    // per-thread activation slice; stride 51 -> gcd(51,32)=1 -> 2-way bank aliasing (free)
    __shared__ float h_lds[256 * 51];
    __shared__ float alpha_lds[52 * HW];   // padded to 52 rows, rows 50/51 = 0
    __shared__ float beta_lds[HW];

    const int tid = threadIdx.x;
    const int c = tid & 3;                 // derivative channel: 0=u,1=u_x,2=u_xx,3=u_xxx

    for (int i = tid; i < 52 * HW; i += 256)
        alpha_lds[i] = (i < HW * HW) ? irk_alpha[i] : 0.0f;
    if (tid < HW) beta_lds[tid] = irk_beta[tid];
    __syncthreads();

    const float lam1 = lambda_1[0];
    const float lam2 = __expf(lambda_2[0]);

    const int pi = blockIdx.x * PPB + (tid >> 2);    // 0..199999 (grid exact)
    const bool br2 = (pi >= NPTS);
    const float x = br2 ? x2[pi - NPTS] : x1[pi];

    float* myh = &h_lds[tid * 51];

    // ---- input layer (1 -> 50): z' = g*w, z'' = z''' = 0; no cross-lane needed ----
    const float xh  = 2.0f * (x - LBc) / (UBc - LBc) - 1.0f;
    const float gsc = 2.0f / (UBc - LBc);
    #pragma unroll 2
    for (int j = 0; j < HW; ++j) {
        float w  = W_in[j];                 // wave-uniform
        float z0 = __builtin_fmaf(xh, w, b_in[j]);
        float z1 = gsc * w;
        float t = fast_tanh(z0);
        float s = 1.0f - t * t;
        float z1sq = z1 * z1;
        float h0 = t;
        float h1 = s * z1;
        float h2 = -2.0f * t * s * z1sq;
        float h3 = s * (6.0f * t * t - 2.0f) * z1sq * z1;
        myh[j] = (c == 0) ? h0 : (c == 1) ? h1 : (c == 2) ? h2 : h3;
    }

    // ---- 4 hidden layers + output layer (50 -> 50, all tanh) ----
    #pragma unroll 1
    for (int layer = 0; layer <= NHID; ++layer) {
        const bool last = (layer == NHID);
        const float* Wp = last ? W_out : (W_hid + layer * HW * HW);
        const float* bp = last ? b_out : (b_hid + layer * HW);

        // bias belongs ONLY to the value channel; derivative channels start at 0
        float z[HW];                        // accumulators, static idx -> registers
        #pragma unroll
        for (int j = 0; j < HW; ++j) z[j] = (c == 0) ? bp[j] : 0.0f;

        #pragma unroll 2
        for (int k = 0; k < HW; ++k) {
            float hk = myh[k];              // own LDS slice, dynamic k
            // row base = 200*k bytes from 256-aligned base -> 8B aligned: float2 ok
            const float2* wr2 = reinterpret_cast<const float2*>(Wp + k * HW);
            #pragma unroll
            for (int j2 = 0; j2 < HW / 2; ++j2) {
                float2 w = wr2[j2];
                z[2 * j2]     = __builtin_fmaf(hk, w.x, z[2 * j2]);
                z[2 * j2 + 1] = __builtin_fmaf(hk, w.y, z[2 * j2 + 1]);
            }
        }

        // nonlinear step: couple channels via quad broadcasts, compute-all + select
        #pragma unroll
        for (int j = 0; j < HW; ++j) {
            float z0b = qperm<0x00>(z[j]);
            float z1b = qperm<0x55>(z[j]);
            float z2b = qperm<0xAA>(z[j]);
            float z3b = qperm<0xFF>(z[j]);
            float t = fast_tanh(z0b);
            float s = 1.0f - t * t;
            float tt = t * t;
            float h0 = t;                                   // u
            float h1 = s * z1b;                             // u_x
            float h2 = s * (z2b - 2.0f * t * z1b * z1b);    // u_xx
            float h3 = s * ((6.0f * tt - 2.0f) * z1b * z1b * z1b
                            - 6.0f * t * z1b * z2b + z3b);  // u_xxx
            float val;
            if (!last) {
                val = (c == 0) ? h0 : (c == 1) ? h1 : (c == 2) ? h2 : h3;
            } else {
                // N_j = -lam1*U*U_x - exp(lam2)*U_xxx  (all lanes hold it)
                val = -lam1 * h0 * h1 - lam2 * h3;
            }
            myh[j] = val;
        }
    }

    // ---- IRK: v_i = sum_j N_j alpha[i][j] (i = 4m+c per lane), S = sum_j N_j beta[j]
    // branch1 residual row = DT*v_i ; branch2 residual row = -DT*(S - v_i)
    float S = 0.0f;
    float v[13];
    #pragma unroll
    for (int m = 0; m < 13; ++m) v[m] = 0.0f;

    #pragma unroll 1
    for (int j = 0; j < HW; ++j) {
        float nj = myh[j];
        S = __builtin_fmaf(nj, beta_lds[j], S);
        #pragma unroll
        for (int m = 0; m < 13; ++m)
            v[m] = __builtin_fmaf(nj, alpha_lds[(4 * m + c) * HW + j], v[m]);
    }

    float acc = 0.0f;
    #pragma unroll
    for (int m = 0; m < 13; ++m) {
        float V = br2 ? (S - v[m]) : v[m];
        if (4 * m + c < HW)                 // rows 50/51 are padding
            acc = __builtin_fmaf(V, V, acc);
    }
    acc *= DTc * DTc;

    #pragma unroll
    for (int off = 1; off < 64; off <<= 1)
        acc += __shfl_xor(acc, off);

    if ((tid & 63) == 0) atomicAdd(out, acc);
}

extern "C" void kernel_launch(void* const* d_in, const int* in_sizes, int n_in,
                              void* d_out, int out_size, void* d_ws, size_t ws_size,
                              hipStream_t stream) {
    const float* x1        = (const float*)d_in[0];
    const float* x2        = (const float*)d_in[1];
    const float* W_in      = (const float*)d_in[2];
    const float* b_in      = (const float*)d_in[3];
    const float* W_hid     = (const float*)d_in[4];
    const float* b_hid     = (const float*)d_in[5];
    const float* W_out     = (const float*)d_in[6];
    const float* b_out     = (const float*)d_in[7];
    const float* lambda_1  = (const float*)d_in[8];
    const float* lambda_2  = (const float*)d_in[9];
    const float* irk_alpha = (const float*)d_in[10];
    const float* irk_beta  = (const float*)d_in[11];
    float* out = (float*)d_out;

    hipMemsetAsync(out, 0, sizeof(float), stream);   // d_out is poisoned 0xAA
    hipLaunchKernelGGL(pinn_kdv_kernel, dim3(NBLK), dim3(256), 0, stream,
                       x1, x2, W_in, b_in, W_hid, b_hid, W_out, b_out,
                       lambda_1, lambda_2, irk_alpha, irk_beta, out);
}